// Round 21
// baseline (438.508 us; speedup 1.0000x reference)
//
#include <hip/hip_runtime.h>
#include <math.h>

#define NS   64
#define NOBS 10000
#define NB   256
#define TMAX 2048

// workspace layout (floats)
#define PIP_OFF 0
#define BF_OFF  64                    // B-fragments of M (bf16-packed), 2048 floats
#define LSE_OFF (64 + 4096)
#define ET_OFF  (64 + 4096 + 64)

typedef float f32x4 __attribute__((ext_vector_type(4)));
typedef short s16x8 __attribute__((ext_vector_type(8)));
typedef int   i32x4 __attribute__((ext_vector_type(4)));

__device__ __forceinline__ float wsum64(float v) {
  v += __shfl_xor(v, 1);
  v += __shfl_xor(v, 2);
  v += __shfl_xor(v, 4);
  v += __shfl_xor(v, 8);
  v += __shfl_xor(v, 16);
  v += __shfl_xor(v, 32);
  return v;
}

// f32 -> bf16 bits, round-to-nearest-even
__device__ __forceinline__ unsigned bf16_rne(float f) {
  unsigned u = __float_as_uint(f);
  return (u + 0x7FFFu + ((u >> 16) & 1u)) >> 16;
}

// ---------------- precompute: softmax(pi), column-softmax(A), B-frags ------
__global__ __launch_bounds__(64) void prep_small(const float* __restrict__ pi,
                                                 const float* __restrict__ A,
                                                 float* __restrict__ ws) {
  const int l = threadIdx.x;  // 0..63
  float p = pi[l];
  float m = p;
  m = fmaxf(m, __shfl_xor(m, 1));
  m = fmaxf(m, __shfl_xor(m, 2));
  m = fmaxf(m, __shfl_xor(m, 4));
  m = fmaxf(m, __shfl_xor(m, 8));
  m = fmaxf(m, __shfl_xor(m, 16));
  m = fmaxf(m, __shfl_xor(m, 32));
  float ex = expf(p - m);
  float s = wsum64(ex);
  ws[PIP_OFF + l] = ex / s;

  __shared__ float Ap[NS * NS];
  float cm = -3.0e38f;
  for (int i = 0; i < NS; ++i) cm = fmaxf(cm, A[i * NS + l]);
  float cs = 0.f;
  for (int i = 0; i < NS; ++i) cs += expf(A[i * NS + l] - cm);
  float inv = 1.0f / cs;
  for (int i = 0; i < NS; ++i) Ap[i * NS + l] = expf(A[i * NS + l] - cm) * inv;
  __syncthreads();

  // B-fragments for mfma_f32_16x16x32_bf16, col-tile Q (output states
  // 16Q..16Q+15), k-chunk kt (k = 32kt..32kt+31). Slot convention: lane l,
  // short-element j <-> k = 32kt + 8*(l>>4) + j; col = 16Q + (l&15).
  // The SAME slot convention is used for the runtime alpha gather, so any
  // unknown hardware slot->k permutation cancels (A/B share the k-map).
  for (int Q = 0; Q < 4; ++Q)
    for (int kt = 0; kt < 2; ++kt)
      for (int mm = 0; mm < 4; ++mm) {
        const int row = 16 * Q + (l & 15);           // output state (B col)
        const int kbase = 32 * kt + 8 * (l >> 4) + 2 * mm;
        const unsigned lo = bf16_rne(Ap[row * NS + kbase]);
        const unsigned hi = bf16_rne(Ap[row * NS + kbase + 1]);
        ws[BF_OFF + (((Q << 1) + kt) * 64 + l) * 4 + mm] =
            __uint_as_float(lo | (hi << 16));
      }
}

// ---------------- precompute: per-state emission logsumexp ----------------
__global__ __launch_bounds__(256) void emis_lse(const float* __restrict__ E,
                                                float* __restrict__ ws) {
  const int s = blockIdx.x;  // state
  const float* row = E + (size_t)s * NOBS;
  __shared__ float red[4];
  float m = -3.0e38f;
  for (int o = threadIdx.x; o < NOBS; o += 256) m = fmaxf(m, row[o]);
  m = fmaxf(m, __shfl_xor(m, 1));
  m = fmaxf(m, __shfl_xor(m, 2));
  m = fmaxf(m, __shfl_xor(m, 4));
  m = fmaxf(m, __shfl_xor(m, 8));
  m = fmaxf(m, __shfl_xor(m, 16));
  m = fmaxf(m, __shfl_xor(m, 32));
  const int wid = threadIdx.x >> 6;
  if ((threadIdx.x & 63) == 0) red[wid] = m;
  __syncthreads();
  m = fmaxf(fmaxf(red[0], red[1]), fmaxf(red[2], red[3]));
  __syncthreads();
  float sum = 0.f;
  for (int o = threadIdx.x; o < NOBS; o += 256) sum += expf(row[o] - m);
  sum = wsum64(sum);
  if ((threadIdx.x & 63) == 0) red[wid] = sum;
  __syncthreads();
  if (threadIdx.x == 0)
    ws[LSE_OFF + s] = m + logf(red[0] + red[1] + red[2] + red[3]);
}

// ---------------- precompute: EprobT[obs*64 + s] = exp(E[s,obs] - lse[s]) ----
__global__ __launch_bounds__(256) void emis_fill(const float* __restrict__ E,
                                                 float* __restrict__ ws) {
  const int idx = blockIdx.x * 256 + threadIdx.x;  // = obs*64 + s
  if (idx >= NS * NOBS) return;
  const int s = idx & 63;
  const int obs = idx >> 6;
  ws[ET_OFF + idx] = expf(E[(size_t)s * NOBS + obs] - ws[LSE_OFF + s]);
}

// ---------------- forward recursion: 1 batch = 1 block = 1 wave ----------------
// Matrix-pipe engine: out = M·alpha via v_mfma_f32_16x16x32_bf16 with
// broadcast-alpha A-operand (all 16 A rows = alpha slice -> every D row is
// the result; lane l takes chain Q=l>>4, reg 0 -- no output shuffle).
// Per step: 16 ds_bpermute gather alpha into A slots (slot (g,j) = alpha
// [32kt+8g+j], matching prep's B arrangement), 8 cvt_pk_bf16, 8 mfma
// (4 col-tile chains x 2 chained k-chunks), 3 uniform selects, e-mul.
// Exact pow-2 rescale every 2 steps (bookkeeping in E2, unchanged).
// Emissions staged per 64-step chunk via global_load_lds (double buffer,
// one vmcnt(0)/chunk); e-reads are plain LDS loads (compiler-managed lgkm
// -- no asm DS ops anywhere, so counters stay coherent with bpermutes).

#define STAGE_CHUNK(XS, HALF) do {                                             \
    _Pragma("unroll")                                                          \
    for (int k_ = 0; k_ < 64; ++k_) {                                          \
      const int xt_ = __builtin_amdgcn_readlane((XS), k_);                     \
      const float* gp_ = ET + ((size_t)(unsigned)xt_ << 6) + lane;             \
      __builtin_amdgcn_global_load_lds(gp_, &ebuf[(((HALF) << 6) + k_) << 6],  \
                                       4, 0, 0);                               \
    } } while (0)

#define CVTPK(D, LO, HI)                                                       \
  asm("v_cvt_pk_bf16_f32 %0, %1, %2" : "=v"(D) : "v"(LO), "v"(HI))

#define STEP(u) do {                                                           \
    const int t_ = t0 + (u);                                                   \
    const float e_ = ebuf[(t_ & 127) * 64 + lane];                             \
    float es_;                                                                 \
    if (((u) & 1) != 0) { /* exact pow-2 rescale every 2 steps */              \
      const unsigned srf_ = __builtin_amdgcn_readfirstlane(__float_as_uint(s));\
      const int se_ = (int)((srf_ >> 23) & 0xFFu) - 127;                       \
      es_ = e_ * __uint_as_float((unsigned)(127 - se_) << 23);                 \
      E2 += se_;                                                               \
    } else { es_ = e_; }                                                       \
    const int sv_ = __float_as_int(s);                                         \
    int bp_[16];                                                               \
    _Pragma("unroll")                                                          \
    for (int j_ = 0; j_ < 16; ++j_)                                            \
      bp_[j_] = __builtin_amdgcn_ds_bpermute(adr[j_], sv_);                    \
    int d0_, d1_, d2_, d3_, d4_, d5_, d6_, d7_;                                \
    CVTPK(d0_, __int_as_float(bp_[0]),  __int_as_float(bp_[1]));               \
    CVTPK(d1_, __int_as_float(bp_[2]),  __int_as_float(bp_[3]));               \
    CVTPK(d2_, __int_as_float(bp_[4]),  __int_as_float(bp_[5]));               \
    CVTPK(d3_, __int_as_float(bp_[6]),  __int_as_float(bp_[7]));               \
    CVTPK(d4_, __int_as_float(bp_[8]),  __int_as_float(bp_[9]));               \
    CVTPK(d5_, __int_as_float(bp_[10]), __int_as_float(bp_[11]));              \
    CVTPK(d6_, __int_as_float(bp_[12]), __int_as_float(bp_[13]));              \
    CVTPK(d7_, __int_as_float(bp_[14]), __int_as_float(bp_[15]));              \
    const i32x4 av0_ = {d0_, d1_, d2_, d3_};   /* kt=0 A-frag */               \
    const i32x4 av1_ = {d4_, d5_, d6_, d7_};   /* kt=1 A-frag */               \
    const s16x8 a0_ = __builtin_bit_cast(s16x8, av0_);                         \
    const s16x8 a1_ = __builtin_bit_cast(s16x8, av1_);                         \
    f32x4 z_ = {0.f, 0.f, 0.f, 0.f};                                           \
    f32x4 c0_ = __builtin_amdgcn_mfma_f32_16x16x32_bf16(a0_, bf0k0, z_, 0,0,0);\
    f32x4 c1_ = __builtin_amdgcn_mfma_f32_16x16x32_bf16(a0_, bf1k0, z_, 0,0,0);\
    f32x4 c2_ = __builtin_amdgcn_mfma_f32_16x16x32_bf16(a0_, bf2k0, z_, 0,0,0);\
    f32x4 c3_ = __builtin_amdgcn_mfma_f32_16x16x32_bf16(a0_, bf3k0, z_, 0,0,0);\
    c0_ = __builtin_amdgcn_mfma_f32_16x16x32_bf16(a1_, bf0k1, c0_, 0, 0, 0);   \
    c1_ = __builtin_amdgcn_mfma_f32_16x16x32_bf16(a1_, bf1k1, c1_, 0, 0, 0);   \
    c2_ = __builtin_amdgcn_mfma_f32_16x16x32_bf16(a1_, bf2k1, c2_, 0, 0, 0);   \
    c3_ = __builtin_amdgcn_mfma_f32_16x16x32_bf16(a1_, bf3k1, c3_, 0, 0, 0);   \
    const float s01_ = c0m ? c1_[0] : c0_[0];                                  \
    const float s23_ = c0m ? c3_[0] : c2_[0];                                  \
    const float fin_ = c1m ? s23_ : s01_;                                      \
    const float w_ = es_ * ((t_ == 0) ? pip : fin_);                           \
    if (t_ == Tn - 1) { vs = w_; e2s = E2; }                                   \
    s = w_;                                                                    \
  } while (0)

__global__ void __attribute__((amdgpu_flat_work_group_size(64, 64)))
__attribute__((amdgpu_waves_per_eu(1, 1)))
hmm_fwd(const int* __restrict__ x, const int* __restrict__ T,
        const float* __restrict__ ws, float* __restrict__ out) {
  const int lane = threadIdx.x;
  const int b = blockIdx.x;
  const int cgrp = lane >> 4;
  const bool c0m = (cgrp & 1) != 0;
  const bool c1m = (cgrp & 2) != 0;
  const float* __restrict__ ET = ws + ET_OFF;
  const int* __restrict__ xb = x + (size_t)b * TMAX;
  const int Tn = T[b];

  __shared__ __align__(16) float ebuf[128 * 64];  // 32 KB, 2 chunk halves

  // B-fragments of M (static, bf16-packed): index (Q*2+kt)
  i32x4 braw[8];
  {
    const i32x4* bsrc = (const i32x4*)(ws + BF_OFF);
#pragma unroll
    for (int i = 0; i < 8; ++i) braw[i] = bsrc[i * 64 + lane];
  }
  const s16x8 bf0k0 = __builtin_bit_cast(s16x8, braw[0]);
  const s16x8 bf0k1 = __builtin_bit_cast(s16x8, braw[1]);
  const s16x8 bf1k0 = __builtin_bit_cast(s16x8, braw[2]);
  const s16x8 bf1k1 = __builtin_bit_cast(s16x8, braw[3]);
  const s16x8 bf2k0 = __builtin_bit_cast(s16x8, braw[4]);
  const s16x8 bf2k1 = __builtin_bit_cast(s16x8, braw[5]);
  const s16x8 bf3k0 = __builtin_bit_cast(s16x8, braw[6]);
  const s16x8 bf3k1 = __builtin_bit_cast(s16x8, braw[7]);

  // bpermute byte-addresses for the alpha gather: slot j (kt=0) pulls lane
  // 8*(lane>>4)+j ; kt=1 pulls +32. Precomputed, statically indexed.
  int adr[16];
  {
    const int g8 = (lane >> 4) << 3;
#pragma unroll
    for (int j = 0; j < 8; ++j) {
      adr[j] = (g8 + j) << 2;
      adr[8 + j] = (32 + g8 + j) << 2;
    }
  }

  const float pip = ws[PIP_OFF + lane];

  // stage chunk 0, drain
  int xcur = xb[lane];
  STAGE_CHUNK(xcur, 0);
  int xnext = xb[64 + lane];
  asm volatile("s_waitcnt vmcnt(0)" ::: "memory");

  float s = 1.0f;   // exponent 0 -> se=0 at t=0
  float vs = 0.f;
  int E2 = 0, e2s = 0;

  const int nch = (Tn + 63) >> 6;
  for (int c = 0; c < nch; ++c) {
    const int tb = c << 6;
    if (c + 1 < TMAX / 64) STAGE_CHUNK(xnext, (c + 1) & 1);
    xnext = ((c + 2) < TMAX / 64) ? xb[((c + 2) << 6) + lane] : 0;
#pragma unroll 1
    for (int gp = 0; gp < 16; ++gp) {
      const int t0 = tb + (gp << 2);
      STEP(0); STEP(1); STEP(2); STEP(3);
    }
    // drain staging of chunk c+1 before its first e-read next iteration
    asm volatile("s_waitcnt vmcnt(0)" ::: "memory");
  }

  const float sf = wsum64(vs);
  if (lane == 0) {
    const double lp = (double)logf(sf) + (double)e2s * 0.6931471805599453;
    out[b] = (float)lp;
  }
}

extern "C" void kernel_launch(void* const* d_in, const int* in_sizes, int n_in,
                              void* d_out, int out_size, void* d_ws, size_t ws_size,
                              hipStream_t stream) {
  const int*   x  = (const int*)d_in[0];
  const int*   T  = (const int*)d_in[1];
  const float* pi = (const float*)d_in[2];
  const float* A  = (const float*)d_in[3];
  const float* E  = (const float*)d_in[4];
  float* out = (float*)d_out;
  float* ws  = (float*)d_ws;

  prep_small<<<1, 64, 0, stream>>>(pi, A, ws);
  emis_lse<<<NS, 256, 0, stream>>>(E, ws);
  emis_fill<<<(NS * NOBS + 255) / 256, 256, 0, stream>>>(E, ws);
  hmm_fwd<<<NB, 64, 0, stream>>>(x, T, ws, out);
}

// Round 22
// 374.286 us; speedup vs baseline: 1.1716x; 1.1716x over previous
//
#include <hip/hip_runtime.h>
#include <math.h>

#define NS   64
#define NOBS 10000
#define NB   256
#define TMAX 2048

// workspace layout (floats)
#define PIP_OFF 0
#define ASW_OFF 64                    // group-permuted, k-pair-interleaved A
#define LSE_OFF (64 + 4096)
#define ET_OFF  (64 + 4096 + 64)

__device__ __forceinline__ float wsum64(float v) {
  v += __shfl_xor(v, 1);
  v += __shfl_xor(v, 2);
  v += __shfl_xor(v, 4);
  v += __shfl_xor(v, 8);
  v += __shfl_xor(v, 16);
  v += __shfl_xor(v, 32);
  return v;
}

// DPP row_ror:N within 16-lane rows. Direction probed at prep time.
#define DPPROR(S, N)                                                           \
  __int_as_float(__builtin_amdgcn_update_dpp(                                  \
      0, __float_as_int(S), 0x120 + (N), 0xF, 0xF, true))

// ---------------- precompute: softmax(pi), column-softmax(A), swizzle ------
__global__ __launch_bounds__(64) void prep_small(const float* __restrict__ pi,
                                                 const float* __restrict__ A,
                                                 float* __restrict__ ws) {
  const int l = threadIdx.x;  // 0..63
  const int r = l & 15, c = l >> 4;
  float p = pi[l];
  float m = p;
  m = fmaxf(m, __shfl_xor(m, 1));
  m = fmaxf(m, __shfl_xor(m, 2));
  m = fmaxf(m, __shfl_xor(m, 4));
  m = fmaxf(m, __shfl_xor(m, 8));
  m = fmaxf(m, __shfl_xor(m, 16));
  m = fmaxf(m, __shfl_xor(m, 32));
  float ex = expf(p - m);
  float s = wsum64(ex);
  ws[PIP_OFF + l] = ex / s;

  __shared__ float Ap[NS * NS];
  float cm = -3.0e38f;
  for (int i = 0; i < NS; ++i) cm = fmaxf(cm, A[i * NS + l]);
  float cs = 0.f;
  for (int i = 0; i < NS; ++i) cs += expf(A[i * NS + l] - cm);
  float inv = 1.0f / cs;
  for (int i = 0; i < NS; ++i) Ap[i * NS + l] = expf(A[i * NS + l] - cm) * inv;
  __syncthreads();

  // probe the hardware's row_ror direction: does lane l receive (l-1)&15 ?
  const int probe = __builtin_amdgcn_update_dpp(0, l, 0x121, 0xF, 0xF, true);
  const int dir = ((probe & 15) == ((r - 1) & 15)) ? 1 : -1;  // uniform

  // group-permuted (slot m holds row-group c^m: q0/q1 = keep pair, q2/q3 =
  // give pair, R19-proven) + k-pair interleave for packed math:
  // float idx l*64 + m*16 + 2j   = A_{c^m}(k=j)    (pk lo lane)
  //           l*64 + m*16 + 2j+1 = A_{c^m}(k=j+8)  (pk hi lane)
  for (int m2 = 0; m2 < 4; ++m2)
    for (int j = 0; j < 8; ++j) {
      const int row = (r + 16 * (c ^ m2)) * NS;
      ws[ASW_OFF + l * 64 + m2 * 16 + 2 * j] =
          Ap[row + (16 * c + ((r - dir * j) & 15))];
      ws[ASW_OFF + l * 64 + m2 * 16 + 2 * j + 1] =
          Ap[row + (16 * c + ((r - dir * (j + 8)) & 15))];
    }
}

// ---------------- precompute: per-state emission logsumexp ----------------
__global__ __launch_bounds__(256) void emis_lse(const float* __restrict__ E,
                                                float* __restrict__ ws) {
  const int s = blockIdx.x;  // state
  const float* row = E + (size_t)s * NOBS;
  __shared__ float red[4];
  float m = -3.0e38f;
  for (int o = threadIdx.x; o < NOBS; o += 256) m = fmaxf(m, row[o]);
  m = fmaxf(m, __shfl_xor(m, 1));
  m = fmaxf(m, __shfl_xor(m, 2));
  m = fmaxf(m, __shfl_xor(m, 4));
  m = fmaxf(m, __shfl_xor(m, 8));
  m = fmaxf(m, __shfl_xor(m, 16));
  m = fmaxf(m, __shfl_xor(m, 32));
  const int wid = threadIdx.x >> 6;
  if ((threadIdx.x & 63) == 0) red[wid] = m;
  __syncthreads();
  m = fmaxf(fmaxf(red[0], red[1]), fmaxf(red[2], red[3]));
  __syncthreads();
  float sum = 0.f;
  for (int o = threadIdx.x; o < NOBS; o += 256) sum += expf(row[o] - m);
  sum = wsum64(sum);
  if ((threadIdx.x & 63) == 0) red[wid] = sum;
  __syncthreads();
  if (threadIdx.x == 0)
    ws[LSE_OFF + s] = m + logf(red[0] + red[1] + red[2] + red[3]);
}

// ---------------- precompute: EprobT[obs*64 + s] = exp(E[s,obs] - lse[s]) ----
__global__ __launch_bounds__(256) void emis_fill(const float* __restrict__ E,
                                                 float* __restrict__ ws) {
  const int idx = blockIdx.x * 256 + threadIdx.x;  // = obs*64 + s
  if (idx >= NS * NOBS) return;
  const int s = idx & 63;
  const int obs = idx >> 6;
  ws[ET_OFF + idx] = expf(E[(size_t)s * NOBS + obs] - ws[LSE_OFF + s]);
}

// ---------------- forward recursion: 1 batch = 1 block = 1 wave ----------------
// R19 (proven absmax 0.0, 340us) + packed matvec: 64 scalar fma -> 32
// v_pk_fma_f32 in ONE asm blob (4 group-chains interleaved, accumulators
// blob-internal -> no copies). k-halves packed per register pair: lo chain
// == R19's qXa_ (k=0..7, same order), hi == qXb_, q = lo+hi == qa+qb ->
// bitwise identical. rot pairs {rot[j], rot[j+8]} from the same 15 DPP movs.
// Butterfly/rescale/staging byte-identical to R19.

#define PINP(i)                                                                \
  asm volatile("" : "+v"(aw2[(i)].x), "+v"(aw2[(i)].y),                        \
                    "+v"(aw2[(i) + 1].x), "+v"(aw2[(i) + 1].y),                \
                    "+v"(aw2[(i) + 2].x), "+v"(aw2[(i) + 2].y),                \
                    "+v"(aw2[(i) + 3].x), "+v"(aw2[(i) + 3].y))
#define PIN_AW() do { PINP(0); PINP(4); PINP(8); PINP(12);                     \
                      PINP(16); PINP(20); PINP(24); PINP(28); } while (0)

// stage 64 emission rows of a chunk (x values in XS) into half HALF of ebuf
#define STAGE_CHUNK(XS, HALF) do {                                             \
    _Pragma("unroll")                                                          \
    for (int k_ = 0; k_ < 64; ++k_) {                                          \
      const int xt_ = __builtin_amdgcn_readlane((XS), k_);                     \
      const float* gp_ = ET + ((size_t)(unsigned)xt_ << 6) + lane;             \
      __builtin_amdgcn_global_load_lds(gp_, &ebuf[(((HALF) << 6) + k_) << 6],  \
                                       4, 0, 0);                               \
    } } while (0)

#define EREAD(DST, ADDR, IMM)                                                  \
  asm volatile("ds_read_b32 %0, %1 offset:" #IMM : "=v"(DST) : "v"(ADDR))

// all 4 group-chains, 4-way interleaved, packed: %0..%3 accs (float2),
// %4..%35 aw2[0..31], %36..%43 rp[0..7]
#define MV_PK(A0, A1, A2, A3)                                                  \
  asm("v_pk_mul_f32 %0, %4, %36\n\t"                                           \
      "v_pk_mul_f32 %1, %12, %36\n\t"                                          \
      "v_pk_mul_f32 %2, %20, %36\n\t"                                          \
      "v_pk_mul_f32 %3, %28, %36\n\t"                                          \
      "v_pk_fma_f32 %0, %5, %37, %0\n\t"                                       \
      "v_pk_fma_f32 %1, %13, %37, %1\n\t"                                      \
      "v_pk_fma_f32 %2, %21, %37, %2\n\t"                                      \
      "v_pk_fma_f32 %3, %29, %37, %3\n\t"                                      \
      "v_pk_fma_f32 %0, %6, %38, %0\n\t"                                       \
      "v_pk_fma_f32 %1, %14, %38, %1\n\t"                                      \
      "v_pk_fma_f32 %2, %22, %38, %2\n\t"                                      \
      "v_pk_fma_f32 %3, %30, %38, %3\n\t"                                      \
      "v_pk_fma_f32 %0, %7, %39, %0\n\t"                                       \
      "v_pk_fma_f32 %1, %15, %39, %1\n\t"                                      \
      "v_pk_fma_f32 %2, %23, %39, %2\n\t"                                      \
      "v_pk_fma_f32 %3, %31, %39, %3\n\t"                                      \
      "v_pk_fma_f32 %0, %8, %40, %0\n\t"                                       \
      "v_pk_fma_f32 %1, %16, %40, %1\n\t"                                      \
      "v_pk_fma_f32 %2, %24, %40, %2\n\t"                                      \
      "v_pk_fma_f32 %3, %32, %40, %3\n\t"                                      \
      "v_pk_fma_f32 %0, %9, %41, %0\n\t"                                       \
      "v_pk_fma_f32 %1, %17, %41, %1\n\t"                                      \
      "v_pk_fma_f32 %2, %25, %41, %2\n\t"                                      \
      "v_pk_fma_f32 %3, %33, %41, %3\n\t"                                      \
      "v_pk_fma_f32 %0, %10, %42, %0\n\t"                                      \
      "v_pk_fma_f32 %1, %18, %42, %1\n\t"                                      \
      "v_pk_fma_f32 %2, %26, %42, %2\n\t"                                      \
      "v_pk_fma_f32 %3, %34, %42, %3\n\t"                                      \
      "v_pk_fma_f32 %0, %11, %43, %0\n\t"                                      \
      "v_pk_fma_f32 %1, %19, %43, %1\n\t"                                      \
      "v_pk_fma_f32 %2, %27, %43, %2\n\t"                                      \
      "v_pk_fma_f32 %3, %35, %43, %3"                                          \
      : "=&v"(A0), "=&v"(A1), "=&v"(A2), "=&v"(A3)                             \
      : "v"(aw2[0]), "v"(aw2[1]), "v"(aw2[2]), "v"(aw2[3]),                    \
        "v"(aw2[4]), "v"(aw2[5]), "v"(aw2[6]), "v"(aw2[7]),                    \
        "v"(aw2[8]), "v"(aw2[9]), "v"(aw2[10]), "v"(aw2[11]),                  \
        "v"(aw2[12]), "v"(aw2[13]), "v"(aw2[14]), "v"(aw2[15]),                \
        "v"(aw2[16]), "v"(aw2[17]), "v"(aw2[18]), "v"(aw2[19]),                \
        "v"(aw2[20]), "v"(aw2[21]), "v"(aw2[22]), "v"(aw2[23]),                \
        "v"(aw2[24]), "v"(aw2[25]), "v"(aw2[26]), "v"(aw2[27]),                \
        "v"(aw2[28]), "v"(aw2[29]), "v"(aw2[30]), "v"(aw2[31]),                \
        "v"(rp[0]), "v"(rp[1]), "v"(rp[2]), "v"(rp[3]),                        \
        "v"(rp[4]), "v"(rp[5]), "v"(rp[6]), "v"(rp[7]))

#define STEP(u, EC) do {                                                       \
    const int t_ = t0 + (u);                                                   \
    const float e_ = EC[(u)];                                                  \
    float es_;                                                                 \
    if (((u) & 1) != 0) { /* exact pow-2 rescale every 2 steps */              \
      const unsigned srf_ = __builtin_amdgcn_readfirstlane(__float_as_uint(s));\
      const int se_ = (int)((srf_ >> 23) & 0xFFu) - 127;                       \
      es_ = e_ * __uint_as_float((unsigned)(127 - se_) << 23);                 \
      E2 += se_;                                                               \
    } else { es_ = e_; }                                                       \
    float2 rp[8];                                                              \
    rp[0].x = s;            rp[0].y = DPPROR(s, 8);                            \
    rp[1].x = DPPROR(s, 1); rp[1].y = DPPROR(s, 9);                            \
    rp[2].x = DPPROR(s, 2); rp[2].y = DPPROR(s, 10);                           \
    rp[3].x = DPPROR(s, 3); rp[3].y = DPPROR(s, 11);                           \
    rp[4].x = DPPROR(s, 4); rp[4].y = DPPROR(s, 12);                           \
    rp[5].x = DPPROR(s, 5); rp[5].y = DPPROR(s, 13);                           \
    rp[6].x = DPPROR(s, 6); rp[6].y = DPPROR(s, 14);                           \
    rp[7].x = DPPROR(s, 7); rp[7].y = DPPROR(s, 15);                           \
    float2 a0_, a1_, a2_, a3_;                                                 \
    MV_PK(a0_, a1_, a2_, a3_);                                                 \
    const float q0_ = a0_.x + a0_.y;                                           \
    const float q1_ = a1_.x + a1_.y;                                           \
    float q2_ = a2_.x + a2_.y;                                                 \
    float q3_ = a3_.x + a3_.y;                                                 \
    /* stage1 (xor32): give q2 (partner's = my group), q3 (buddy's) */         \
    float t2_, t3_;                                                            \
    asm("v_mov_b32 %0, %1" : "=v"(t2_) : "v"(q2_));                            \
    asm("v_mov_b32 %0, %1" : "=v"(t3_) : "v"(q3_));                            \
    asm("v_permlane32_swap_b32 %0, %1" : "+v"(q2_), "+v"(t2_));                \
    asm("v_permlane32_swap_b32 %0, %1" : "+v"(q3_), "+v"(t3_));                \
    const float pm_ = inA32 ? q2_ : t2_;   /* partner's give A (probed) */     \
    const float pn_ = inA32 ? q3_ : t3_;   /* partner's give B (probed) */     \
    const float ua_ = q0_ + pm_;   /* my group over chunks {c, c^2} */         \
    float ub_ = q1_ + pn_;         /* buddy group over {c, c^2}     */         \
    /* stage2 (xor16): give ub (partner's = my group over {c^1, c^3}) */       \
    float tg_;                                                                 \
    asm("v_mov_b32 %0, %1" : "=v"(tg_) : "v"(ub_));                            \
    asm("v_permlane16_swap_b32 %0, %1" : "+v"(ub_), "+v"(tg_));                \
    const float pg_ = inA16 ? ub_ : tg_;   /* partner's give (probed) */       \
    const float fin_ = ua_ + pg_;                                              \
    const float w_ = es_ * ((t_ == 0) ? pip : fin_);                           \
    if (t_ == Tn - 1) { vs = w_; e2s = E2; }                                   \
    s = w_;                                                                    \
  } while (0)

// one 4-step group: issue next group's 4 e-reads, exact-wait current's, run 4
#define GROUP(T0, ECUR, ENXT) do {                                             \
    const int t0 = (T0);                                                       \
    { const unsigned ea_ =                                                     \
          ebase + ((unsigned)(((t0 + 4) & 127)) << 8) + ((unsigned)lane << 2); \
      EREAD(ENXT[0], ea_, 0);   EREAD(ENXT[1], ea_, 256);                      \
      EREAD(ENXT[2], ea_, 512); EREAD(ENXT[3], ea_, 768); }                    \
    asm volatile("s_waitcnt lgkmcnt(4)");                                      \
    __builtin_amdgcn_sched_barrier(0);                                         \
    STEP(0, ECUR); STEP(1, ECUR); STEP(2, ECUR); STEP(3, ECUR);                \
  } while (0)

__global__ void __attribute__((amdgpu_flat_work_group_size(64, 64)))
__attribute__((amdgpu_waves_per_eu(1, 1)))
hmm_fwd(const int* __restrict__ x, const int* __restrict__ T,
        const float* __restrict__ ws, float* __restrict__ out) {
  const int lane = threadIdx.x;
  const int b = blockIdx.x;
  const float* __restrict__ ET = ws + ET_OFF;
  const int* __restrict__ xb = x + (size_t)b * TMAX;
  const int Tn = T[b];

  __shared__ __align__(16) float ebuf[128 * 64];  // 32 KB, 2 chunk halves
  const unsigned ebase = (unsigned)(size_t)ebuf;  // flat->LDS trunc

  // probe swap routing (R11 lesson: never assume direction semantics)
  bool inA32, inA16;
  {
    float qa = __int_as_float(lane), qb;
    asm("v_mov_b32 %0, %1" : "=v"(qb) : "v"(qa));
    asm("v_permlane32_swap_b32 %0, %1" : "+v"(qa), "+v"(qb));
    inA32 = (__float_as_int(qa) == (lane ^ 32));
    float pa = __int_as_float(lane), pb;
    asm("v_mov_b32 %0, %1" : "=v"(pb) : "v"(pa));
    asm("v_permlane16_swap_b32 %0, %1" : "+v"(pa), "+v"(pb));
    inA16 = (__float_as_int(pa) == (lane ^ 16));
  }

  // group-permuted, k-pair-interleaved A tile: aw2[g*8+j] = {A(k=j), A(k=j+8)}
  float2 aw2[32];
  {
    const float4* ar = (const float4*)(ws + ASW_OFF + lane * 64);
#pragma unroll
    for (int q = 0; q < 16; ++q) {
      float4 f = ar[q];
      aw2[2 * q]     = make_float2(f.x, f.y);
      aw2[2 * q + 1] = make_float2(f.z, f.w);
    }
  }
  PIN_AW();

  const float pip = ws[PIP_OFF + lane];

  // stage chunk 0, drain, prime group-0 e-reads
  int xcur = xb[lane];
  STAGE_CHUNK(xcur, 0);
  int xnext = xb[64 + lane];
  asm volatile("s_waitcnt vmcnt(0)" ::: "memory");

  float eA[4], eB[4];
  {
    const unsigned ea_ = ebase + ((unsigned)lane << 2);
    EREAD(eA[0], ea_, 0);   EREAD(eA[1], ea_, 256);
    EREAD(eA[2], ea_, 512); EREAD(eA[3], ea_, 768);
  }

  float s = 1.0f;   // exponent 0 -> se=0 at t=0
  float vs = 0.f;
  int E2 = 0, e2s = 0;

  const int nch = (Tn + 63) >> 6;
  for (int c = 0; c < nch; ++c) {
    const int tb = c << 6;
    if (c + 1 < TMAX / 64) STAGE_CHUNK(xnext, (c + 1) & 1);
    xnext = ((c + 2) < TMAX / 64) ? xb[((c + 2) << 6) + lane] : 0;
#pragma unroll 1
    for (int gp = 0; gp < 7; ++gp) {    // groups 0..13
      GROUP(tb + (gp << 3), eA, eB);
      GROUP(tb + (gp << 3) + 4, eB, eA);
    }
    GROUP(tb + 56, eA, eB);             // group 14
    // drain staging of chunk c+1 before group 15 issues next-chunk reads
    asm volatile("s_waitcnt vmcnt(0)" ::: "memory");
    GROUP(tb + 60, eB, eA);             // group 15 (loads eA for next chunk)
  }

  const float sf = wsum64(vs);
  if (lane == 0) {
    const double lp = (double)logf(sf) + (double)e2s * 0.6931471805599453;
    out[b] = (float)lp;
  }
}

extern "C" void kernel_launch(void* const* d_in, const int* in_sizes, int n_in,
                              void* d_out, int out_size, void* d_ws, size_t ws_size,
                              hipStream_t stream) {
  const int*   x  = (const int*)d_in[0];
  const int*   T  = (const int*)d_in[1];
  const float* pi = (const float*)d_in[2];
  const float* A  = (const float*)d_in[3];
  const float* E  = (const float*)d_in[4];
  float* out = (float*)d_out;
  float* ws  = (float*)d_ws;

  prep_small<<<1, 64, 0, stream>>>(pi, A, ws);
  emis_lse<<<NS, 256, 0, stream>>>(E, ws);
  emis_fill<<<(NS * NOBS + 255) / 256, 256, 0, stream>>>(E, ws);
  hmm_fwd<<<NB, 64, 0, stream>>>(x, T, ws, out);
}